// Round 12
// baseline (43.373 us; speedup 1.0000x reference)
//
#include <hip/hip_runtime.h>

#define GRIDD  76                 // grid dim (H = W)
#define NROWS  255                // anchors(3) * attrs(85)
#define GG     (GRIDD * GRIDD)    // 5776
#define QROWS  64                 // rem rows per block (quarter unit)
#define QQ     (QROWS * 19)       // 1216 float4 quads per slab
#define QDW    (QROWS * GRIDD)    // 4864 dwords = 19456 B -> 8 blocks/CU

typedef __attribute__((address_space(3))) unsigned lds_u32;
typedef __attribute__((address_space(1))) unsigned glb_u32;

__device__ __forceinline__ void gll16(const float* g, float* l) {
    // async global->LDS, 16B/lane; LDS dest = wave-uniform base + lane*16
    __builtin_amdgcn_global_load_lds((const glb_u32*)g, (lds_u32*)l, 16, 0, 0);
}

__global__ __launch_bounds__(256, 8) void yolo_head_kernel(
    const float* __restrict__ x, const int* __restrict__ dimp,
    float* __restrict__ out)
{
    __shared__ float buf[QDW];    // zero-pad [64][76] slab, linear = gll16-compatible
    // XCD-bijective swizzle (4864 = 8*608): the 4 quarters of a (b,h) and
    // neighboring h stay on ONE XCD L2 and run concurrently -> seam lines merge.
    const unsigned lb    = (blockIdx.x & 7u) * 608u + (blockIdx.x >> 3);
    const unsigned b     = lb / 304u;
    const unsigned hq    = lb - b * 304u;
    const unsigned h     = hq >> 2;
    const unsigned q     = hq & 3u;
    const unsigned rbase = (q == 3u) ? 191u : (q << 6);  // q3 overlaps row 191 (idempotent)
    const unsigned t     = threadIdx.x;
    const unsigned wid   = t >> 6;
    const unsigned lane  = t & 63u;
    const float stride   = (float)(*dimp / GRIDD);       // 608/76 = 8
    const float fh       = (float)h;

    // ---- phase 1: async-stage [64 rem][76 w], linear LDS dest ----
    const float* __restrict__ src = x + (size_t)(b * NROWS + rbase) * GG + h * GRIDD;
    #pragma unroll
    for (unsigned k = 0; k < 5u; ++k) {
        unsigned i = k * 256u + (wid << 6) + lane;       // quad 0..1215
        if (i < QQ) {                                    // k=4: waves 0-2 (uniform)
            unsigned row = i / 19u;
            unsigned qc  = i - row * 19u;
            gll16(src + (size_t)row * GG + (qc << 2),
                  buf + (size_t)(k * 256u + (wid << 6)) * 4u);  // +lane*16B implicit
        }
    }
    __syncthreads();                                     // drains vmcnt -> slab ready

    // ---- phase 2: lane = slab row; all attr logic lane-fixed, hoisted ----
    const unsigned rem  = rbase + lane;                  // 0..254
    const unsigned a    = (rem >= 170u) ? 2u : ((rem >= 85u) ? 1u : 0u);
    const unsigned attr = rem - a * 85u;
    const bool  wh  = (attr == 2u) | (attr == 3u);
    const bool  isx = (attr == 0u);
    float anc = 0.f;
    if (attr == 2u) anc = (a == 0u) ? 12.f : ((a == 1u) ? 19.f : 40.f);
    if (attr == 3u) anc = (a == 0u) ? 16.f : ((a == 1u) ? 36.f : 28.f);
    const float mB    = -0.1f * stride;
    const float slog  = wh ? 1.44269504f : -1.44269504f; // +-log2(e) premultiplied
    const float A2    = wh ? anc : ((attr < 2u) ? 1.2f * stride : 1.f);
    const float wsel  = isx ? stride : 0.f;
    const float basef = (attr == 1u) ? fmaf(fh, stride, mB) : (isx ? mB : 0.f);
    float* __restrict__ dst = out + (size_t)(b * GRIDD + h) * (GRIDD * NROWS) + rem;

    // Batch ALL LDS reads up front (20 VGPRs of ILP), then math + nt stores.
    float4 vv[5];
    #pragma unroll
    for (unsigned j = 0; j < 5u; ++j) {
        const unsigned tt = wid + (j << 2);              // quad col 0..18
        if (tt < 19u)                                    // j=4: waves 0-2 (uniform)
            // lane stride 19 quads (3 mod 8) -> uniform bank spread, 0 conflicts
            vv[j] = *reinterpret_cast<const float4*>(
                buf + (size_t)lane * GRIDD + (tt << 2));
    }
    #pragma unroll
    for (unsigned j = 0; j < 5u; ++j) {
        const unsigned tt = wid + (j << 2);
        if (tt < 19u) {
            #pragma unroll
            for (unsigned i = 0; i < 4u; ++i) {
                const float v  = (i == 0) ? vv[j].x : (i == 1) ? vv[j].y
                               : (i == 2) ? vv[j].z : vv[j].w;
                const float uf = (float)((tt << 2) + i);
                const float e2 = exp2f(v * slog);        // v_mul + v_exp
                const float sg = __builtin_amdgcn_rcpf(1.0f + e2);
                const float qv = wh ? e2 : sg;           // lane-const cndmask
                const float o  = fmaf(qv, A2, fmaf(uf, wsel, basef));
                // Non-temporal: output is write-once/never-read. Keeps the 94MB
                // input L3-resident across replays -> steady-state FETCH ~0.
                __builtin_nontemporal_store(o, dst + (size_t)((tt << 2) + i) * NROWS);
            }
        }
    }
}

extern "C" void kernel_launch(void* const* d_in, const int* in_sizes, int n_in,
                              void* d_out, int out_size, void* d_ws, size_t ws_size,
                              hipStream_t stream) {
    const float* x  = (const float*)d_in[0];
    const int* dimp = (const int*)d_in[1];
    float* out      = (float*)d_out;
    const int B = in_sizes[0] / (NROWS * GG);   // 16
    yolo_head_kernel<<<B * GRIDD * 4, 256, 0, stream>>>(x, dimp, out);
}

// Round 13
// 33.001 us; speedup vs baseline: 1.3143x; 1.3143x over previous
//
#include <hip/hip_runtime.h>

#define GRIDD  76                 // grid dim (H = W)
#define NROWS  255                // anchors(3) * attrs(85)
#define GG     (GRIDD * GRIDD)    // 5776
#define QROWS  64                 // rem rows per block (quarter unit)
#define QQ     (QROWS * 19)       // 1216 float4 quads per slab
#define QDW    (QROWS * GRIDD)    // 4864 dwords = 19456 B -> 8 blocks/CU

typedef __attribute__((address_space(3))) unsigned lds_u32;
typedef __attribute__((address_space(1))) unsigned glb_u32;

__device__ __forceinline__ void gll16(const float* g, float* l) {
    // async global->LDS, 16B/lane; LDS dest = wave-uniform base + lane*16
    __builtin_amdgcn_global_load_lds((const glb_u32*)g, (lds_u32*)l, 16, 0, 0);
}

__global__ __launch_bounds__(256, 8) void yolo_head_kernel(
    const float* __restrict__ x, const int* __restrict__ dimp,
    float* __restrict__ out)
{
    __shared__ float buf[QDW];    // zero-pad [64][76] slab, linear = gll16-compatible
    // XCD-bijective swizzle (4864 = 8*608): the 4 quarters of a (b,h) and
    // neighboring h stay on ONE XCD L2 and run concurrently -> seam lines merge.
    const unsigned lb    = (blockIdx.x & 7u) * 608u + (blockIdx.x >> 3);
    const unsigned b     = lb / 304u;
    const unsigned hq    = lb - b * 304u;
    const unsigned h     = hq >> 2;
    const unsigned q     = hq & 3u;
    const unsigned rbase = (q == 3u) ? 191u : (q << 6);  // q3 overlaps row 191 (idempotent)
    const unsigned t     = threadIdx.x;
    const unsigned wid   = t >> 6;
    const unsigned lane  = t & 63u;
    const float stride   = (float)(*dimp / GRIDD);       // 608/76 = 8
    const float fh       = (float)h;

    // ---- phase 1: async-stage [64 rem][76 w], linear LDS dest ----
    const float* __restrict__ src = x + (size_t)(b * NROWS + rbase) * GG + h * GRIDD;
    #pragma unroll
    for (unsigned k = 0; k < 5u; ++k) {
        unsigned i = k * 256u + (wid << 6) + lane;       // quad 0..1215
        if (i < QQ) {                                    // k=4: waves 0-2 (uniform)
            unsigned row = i / 19u;
            unsigned qc  = i - row * 19u;
            gll16(src + (size_t)row * GG + (qc << 2),
                  buf + (size_t)(k * 256u + (wid << 6)) * 4u);  // +lane*16B implicit
        }
    }
    __syncthreads();                                     // drains vmcnt -> slab ready

    // ---- phase 2: lane = slab row; all attr logic lane-fixed, hoisted ----
    const unsigned rem  = rbase + lane;                  // 0..254
    const unsigned a    = (rem >= 170u) ? 2u : ((rem >= 85u) ? 1u : 0u);
    const unsigned attr = rem - a * 85u;
    const bool  wh  = (attr == 2u) | (attr == 3u);
    const bool  isx = (attr == 0u);
    float anc = 0.f;
    if (attr == 2u) anc = (a == 0u) ? 12.f : ((a == 1u) ? 19.f : 40.f);
    if (attr == 3u) anc = (a == 0u) ? 16.f : ((a == 1u) ? 36.f : 28.f);
    const float mB    = -0.1f * stride;
    const float slog  = wh ? 1.44269504f : -1.44269504f; // +-log2(e) premultiplied
    const float A2    = wh ? anc : ((attr < 2u) ? 1.2f * stride : 1.f);
    const float wsel  = isx ? stride : 0.f;
    const float basef = (attr == 1u) ? fmaf(fh, stride, mB) : (isx ? mB : 0.f);
    float* __restrict__ dst = out + (size_t)(b * GRIDD + h) * (GRIDD * NROWS) + rem;

    // Batch ALL LDS reads up front (20 VGPRs of ILP), then math + stores.
    float4 vv[5];
    #pragma unroll
    for (unsigned j = 0; j < 5u; ++j) {
        const unsigned tt = wid + (j << 2);              // quad col 0..18
        if (tt < 19u)                                    // j=4: waves 0-2 (uniform)
            // lane stride 19 quads (3 mod 8) -> uniform bank spread, 0 conflicts
            vv[j] = *reinterpret_cast<const float4*>(
                buf + (size_t)lane * GRIDD + (tt << 2));
    }
    #pragma unroll
    for (unsigned j = 0; j < 5u; ++j) {
        const unsigned tt = wid + (j << 2);
        if (tt < 19u) {
            #pragma unroll
            for (unsigned i = 0; i < 4u; ++i) {
                const float v  = (i == 0) ? vv[j].x : (i == 1) ? vv[j].y
                               : (i == 2) ? vv[j].z : vv[j].w;
                const float uf = (float)((tt << 2) + i);
                const float e2 = exp2f(v * slog);        // v_mul + v_exp
                const float sg = __builtin_amdgcn_rcpf(1.0f + e2);
                const float qv = wh ? e2 : sg;           // lane-const cndmask
                const float o  = fmaf(qv, A2, fmaf(uf, wsel, basef));
                dst[(size_t)((tt << 2) + i) * NROWS] = o;   // 64-rem 256B runs
            }
        }
    }
}

extern "C" void kernel_launch(void* const* d_in, const int* in_sizes, int n_in,
                              void* d_out, int out_size, void* d_ws, size_t ws_size,
                              hipStream_t stream) {
    const float* x  = (const float*)d_in[0];
    const int* dimp = (const int*)d_in[1];
    float* out      = (float*)d_out;
    const int B = in_sizes[0] / (NROWS * GG);   // 16
    yolo_head_kernel<<<B * GRIDD * 4, 256, 0, stream>>>(x, dimp, out);
}